// Round 3
// baseline (56.532 us; speedup 1.0000x reference)
//
#include <hip/hip_runtime.h>

// ROI max-pool (aspect-preserving "OCR" variant).
// feats: (B=4, C=128, H=64, W=512) fp32
// rois:  (N, 5) fp32 = [batch, x1, y1, x2, y2] image coords, spatial scale 0.25
// out:   (N, C, PH=8, PW=32) fp32
//
// Block = 128 threads = (4 ph-rows x 32 pw) for one (roi, 16-channel group).
// ROI params + 16 channel-plane bases are block-uniform (SGPR). Inner loop per
// bin pixel: 1 voffset + 16 scalar-base loads (16-deep MLP) + 16 v_max.

#define PHB 8
#define PWB 32
#define CPT 16            // channels per thread
#define BLK 128           // threads per block (2 waves)

__global__ __launch_bounds__(BLK) void ocr_roi_pool_kernel(
    const float* __restrict__ feats,
    const float* __restrict__ rois,
    float* __restrict__ out,
    int Cc, int Hc, int Wc)
{
#pragma clang fp contract(off)
    const int ngroups = 128 / CPT;                 // 8
    int b   = blockIdx.x;
    int n   = b >> 4;                              // roi index (uniform)
    int rem = b & 15;
    int cg  = rem >> 1;                            // channel group (uniform)
    int phh = rem & 1;                             // which ph half (uniform)
    int c0  = cg * CPT;

    int t  = threadIdx.x;
    int pw = t & 31;
    int ph = (t >> 5) + phh * 4;

    // ---- ROI params: block-uniform -> scalar ----
    const float* r = rois + n * 5;
    int rb  = (int)r[0];
    int rsw = (int)floorf(r[1] * 0.25f + 0.5f);
    int rsh = (int)floorf(r[2] * 0.25f + 0.5f);
    int rew = (int)floorf(r[3] * 0.25f + 0.5f);
    int reh = (int)floorf(r[4] * 0.25f + 0.5f);

    int roi_w = max(rew - rsw + 1, 1);
    int roi_h = max(reh - rsh + 1, 1);
    int rpw   = (PHB * roi_w + roi_h - 1) / roi_h;

    float bsh = (float)roi_h / (float)PHB;
    float bsw = (float)roi_w / (float)rpw;

    // ---- per-thread bin bounds (exact reference math) ----
    int hs = (int)floorf((float)ph * bsh) + rsh;
    int he = (int)ceilf((float)(ph + 1) * bsh) + rsh;
    int ws = (int)floorf((float)pw * bsw) + rsw;
    int we = (int)ceilf((float)(pw + 1) * bsw) + rsw;

    hs = min(max(hs, 0), Hc);
    he = min(max(he, 0), Hc);
    ws = min(max(ws, 0), Wc);
    we = min(max(we, 0), Wc);

    bool pad   = (ws >= rew);
    bool empty = (he <= hs) || (we <= ws);

    // ---- 16 uniform channel-plane base pointers (SGPR) ----
    const float* base[CPT];
#pragma unroll
    for (int k = 0; k < CPT; ++k)
        base[k] = feats + ((size_t)(rb * Cc + c0 + k) * Hc) * Wc;

    float m[CPT];
#pragma unroll
    for (int k = 0; k < CPT; ++k) m[k] = -1e37f;

    if (!(pad || empty)) {
        for (int h = hs; h < he; ++h) {
            int rowoff = h * Wc;
            for (int w = ws; w < we; ++w) {
                int off = rowoff + w;
#pragma unroll
                for (int k = 0; k < CPT; ++k)
                    m[k] = fmaxf(m[k], base[k][off]);
            }
        }
    } else {
#pragma unroll
        for (int k = 0; k < CPT; ++k) m[k] = 0.0f;
    }

    // ---- store: (n, c, ph, pw) ----
    size_t obase = ((size_t)n * Cc + c0) * (PHB * PWB) + ph * PWB + pw;
#pragma unroll
    for (int k = 0; k < CPT; ++k)
        out[obase + (size_t)k * (PHB * PWB)] = m[k];
}

extern "C" void kernel_launch(void* const* d_in, const int* in_sizes, int n_in,
                              void* d_out, int out_size, void* d_ws, size_t ws_size,
                              hipStream_t stream) {
    const float* feats = (const float*)d_in[0];
    const float* rois  = (const float*)d_in[1];
    float* out = (float*)d_out;

    const int Cc = 128, Hc = 64, Wc = 512;
    int nroi = in_sizes[1] / 5;
    int blocks = nroi * (Cc / CPT) * 2;   // 8 channel groups x 2 ph halves

    ocr_roi_pool_kernel<<<blocks, BLK, 0, stream>>>(feats, rois, out, Cc, Hc, Wc);
}

// Round 4
// 54.026 us; speedup vs baseline: 1.0464x; 1.0464x over previous
//
#include <hip/hip_runtime.h>

// ROI max-pool (aspect-preserving "OCR" variant) — separable two-phase version.
// feats: (B=4, C=128, H=64, W=512) fp32
// rois:  (N, 5) fp32 = [batch, x1, y1, x2, y2] image coords, spatial scale 0.25
// out:   (N, C, PH=8, PW=32) fp32
//
// out[n,c,ph,pw] = max_{w in [ws,we)} max_{h in [hs,he)} feats[rb,c,h,w]  (or 0)
// Block = (roi, ph, channel-half of 64). Phase 1: rowmax over h staged to LDS
// with coalesced 32-lane-contiguous loads. Phase 2: tiny w-max from LDS.

#define PHB 8
#define PWB 32
#define CHB 64          // channels per block
#define WST 120         // staged width cap (data bound: ceil(32*bsw) <= 108)
#define BLK 256

__global__ __launch_bounds__(BLK) void ocr_roi_pool_kernel(
    const float* __restrict__ feats,
    const float* __restrict__ rois,
    float* __restrict__ out,
    int Cc, int Hc, int Wc)
{
#pragma clang fp contract(off)
    __shared__ float smax[CHB * WST];

    int b     = blockIdx.x;            // ((n*8 + ph)*2 + chalf)
    int chalf = b & 1;
    int ph    = (b >> 1) & 7;
    int n     = b >> 4;
    int c0    = chalf * CHB;

    // ---- ROI params: block-uniform -> scalar ----
    const float* r = rois + n * 5;
    int rb  = (int)r[0];
    int rsw = (int)floorf(r[1] * 0.25f + 0.5f);
    int rsh = (int)floorf(r[2] * 0.25f + 0.5f);
    int rew = (int)floorf(r[3] * 0.25f + 0.5f);
    int reh = (int)floorf(r[4] * 0.25f + 0.5f);

    int roi_w = max(rew - rsw + 1, 1);
    int roi_h = max(reh - rsh + 1, 1);
    int rpw   = (PHB * roi_w + roi_h - 1) / roi_h;

    float bsh = (float)roi_h / (float)PHB;
    float bsw = (float)roi_w / (float)rpw;

    // h-range for this ph (uniform over block), exact reference math
    int hs = (int)floorf((float)ph * bsh) + rsh;
    int he = (int)ceilf((float)(ph + 1) * bsh) + rsh;
    hs = min(max(hs, 0), Hc);
    he = min(max(he, 0), Hc);

    // staged w-window [wlo, whi) covers every bin's [ws,we) (we monotone in pw)
    int wlo = min(max(rsw, 0), Wc);
    int whi = (int)ceilf((float)PWB * bsw) + rsw;
    whi = min(max(whi, 0), Wc);
    int wwid = whi - wlo;              // <= 108 by data bounds

    int t      = threadIdx.x;
    int lane_w = t & 31;
    int cslot  = t >> 5;               // 0..7

    // ---- Phase 1: rowmax -> LDS ----
    if (he > hs && wwid > 0) {
        const float* plane0 =
            feats + ((size_t)(rb * Cc + c0 + cslot) * Hc) * Wc;
        for (int wp = lane_w; wp < wwid; wp += 32) {
            float rm[8];
#pragma unroll
            for (int j = 0; j < 8; ++j) rm[j] = -1e37f;
            for (int h = hs; h < he; ++h) {
                size_t rowoff = (size_t)h * Wc + wlo + wp;
#pragma unroll
                for (int j = 0; j < 8; ++j)
                    rm[j] = fmaxf(rm[j], plane0[(size_t)(8 * j) * Hc * Wc + rowoff]);
            }
#pragma unroll
            for (int j = 0; j < 8; ++j)
                smax[(cslot + 8 * j) * WST + wp] = rm[j];
        }
    }
    __syncthreads();

    // ---- Phase 2: colmax from LDS, store ----
    int pw = lane_w;
    int ws = (int)floorf((float)pw * bsw) + rsw;
    int we = (int)ceilf((float)(pw + 1) * bsw) + rsw;
    ws = min(max(ws, 0), Wc);
    we = min(max(we, 0), Wc);

    bool pad   = (ws >= rew);
    bool empty = (he <= hs) || (we <= ws);

    size_t obase = (((size_t)n * Cc + c0 + cslot) * PHB + ph) * PWB + pw;
    if (pad || empty) {
#pragma unroll
        for (int j = 0; j < 8; ++j)
            out[obase + (size_t)(8 * j) * (PHB * PWB)] = 0.0f;
    } else {
#pragma unroll
        for (int j = 0; j < 8; ++j) {
            int cl = cslot + 8 * j;
            float m = -1e37f;
            for (int w = ws; w < we; ++w)
                m = fmaxf(m, smax[cl * WST + (w - wlo)]);
            out[obase + (size_t)(8 * j) * (PHB * PWB)] = m;
        }
    }
}

extern "C" void kernel_launch(void* const* d_in, const int* in_sizes, int n_in,
                              void* d_out, int out_size, void* d_ws, size_t ws_size,
                              hipStream_t stream) {
    const float* feats = (const float*)d_in[0];
    const float* rois  = (const float*)d_in[1];
    float* out = (float*)d_out;

    const int Cc = 128, Hc = 64, Wc = 512;
    int nroi = in_sizes[1] / 5;
    int blocks = nroi * PHB * 2;   // (n, ph, channel-half)

    ocr_roi_pool_kernel<<<blocks, BLK, 0, stream>>>(feats, rois, out, Cc, Hc, Wc);
}

// Round 5
// 35.848 us; speedup vs baseline: 1.5770x; 1.5071x over previous
//
#include <hip/hip_runtime.h>

// ROI max-pool (aspect-preserving "OCR" variant) — separable two-phase, v2.
// feats: (B=4, C=128, H=64, W=512) fp32
// rois:  (N, 5) fp32 = [batch, x1, y1, x2, y2] image coords, spatial scale 0.25
// out:   (N, C, PH=8, PW=32) fp32
//
// Block = (roi, ph, channel-quarter of 32). 256 thr = 32 w-lanes x 8 cslots,
// each cslot covers 4 channels (stride 8). Phase 1: rowmax over h -> LDS,
// coalesced; h-loop unrolled x2 (idempotent max). Phase 2: w-max from LDS.
// LDS 14 KB -> occupancy capped by waves (8 blocks/CU), not LDS.

#define PHB 8
#define PWB 32
#define CHB 32          // channels per block
#define WST 112         // staged width cap (bsw <= 27/8 -> ceil(32*bsw) <= 108)
#define BLK 256

__global__ __launch_bounds__(BLK) void ocr_roi_pool_kernel(
    const float* __restrict__ feats,
    const float* __restrict__ rois,
    float* __restrict__ out,
    int Cc, int Hc, int Wc)
{
#pragma clang fp contract(off)
    __shared__ float smax[CHB * WST];

    int b  = blockIdx.x;               // ((n*8 + ph)*4 + cq)
    int cq = b & 3;
    int ph = (b >> 2) & 7;
    int n  = b >> 5;
    int c0 = cq * CHB;

    // ---- ROI params: block-uniform -> scalar ----
    const float* r = rois + n * 5;
    int rb  = (int)r[0];
    int rsw = (int)floorf(r[1] * 0.25f + 0.5f);
    int rsh = (int)floorf(r[2] * 0.25f + 0.5f);
    int rew = (int)floorf(r[3] * 0.25f + 0.5f);
    int reh = (int)floorf(r[4] * 0.25f + 0.5f);

    int roi_w = max(rew - rsw + 1, 1);
    int roi_h = max(reh - rsh + 1, 1);
    int rpw   = (PHB * roi_w + roi_h - 1) / roi_h;

    float bsh = (float)roi_h / (float)PHB;
    float bsw = (float)roi_w / (float)rpw;

    // h-range for this ph (uniform over block), exact reference math
    int hs = (int)floorf((float)ph * bsh) + rsh;
    int he = (int)ceilf((float)(ph + 1) * bsh) + rsh;
    hs = min(max(hs, 0), Hc);
    he = min(max(he, 0), Hc);

    // staged w-window [wlo, whi): covers every NON-PAD bin's reads.
    // Any read w satisfies w <= rew+3 (bsw <= 3.375) and w < ceil(32*bsw)+rsw.
    int wlo = min(max(rsw, 0), Wc);
    int whi = (int)ceilf((float)PWB * bsw) + rsw;
    whi = min(whi, rew + 4);
    whi = min(max(whi, 0), Wc);
    int wwid = min(whi - wlo, WST);

    int t      = threadIdx.x;
    int lane_w = t & 31;
    int cslot  = t >> 5;               // 0..7

    const int plane_stride = Hc * Wc;  // 32768

    // ---- Phase 1: rowmax -> LDS (h unrolled x2, max is idempotent) ----
    if (he > hs && wwid > 0) {
        const float* plane =
            feats + ((size_t)(rb * Cc + c0 + cslot) * Hc) * Wc;
        for (int wp = lane_w; wp < wwid; wp += 32) {
            float rm[4];
#pragma unroll
            for (int j = 0; j < 4; ++j) rm[j] = -1e37f;
            for (int h = hs; h < he; h += 2) {
                int hb = min(h + 1, he - 1);
                int offa = h  * Wc + wlo + wp;
                int offb = hb * Wc + wlo + wp;
#pragma unroll
                for (int j = 0; j < 4; ++j) {
                    float va = plane[(size_t)(8 * j) * plane_stride + offa];
                    float vb = plane[(size_t)(8 * j) * plane_stride + offb];
                    rm[j] = fmaxf(rm[j], fmaxf(va, vb));
                }
            }
#pragma unroll
            for (int j = 0; j < 4; ++j)
                smax[(cslot + 8 * j) * WST + wp] = rm[j];
        }
    }
    __syncthreads();

    // ---- Phase 2: colmax from LDS, store ----
    int pw = lane_w;
    int ws = (int)floorf((float)pw * bsw) + rsw;
    int we = (int)ceilf((float)(pw + 1) * bsw) + rsw;
    ws = min(max(ws, 0), Wc);
    we = min(max(we, 0), Wc);

    bool pad   = (ws >= rew);
    bool empty = (he <= hs) || (we <= ws);

    size_t obase = (((size_t)n * Cc + c0 + cslot) * PHB + ph) * PWB + pw;
    if (pad || empty) {
#pragma unroll
        for (int j = 0; j < 4; ++j)
            out[obase + (size_t)(8 * j) * (PHB * PWB)] = 0.0f;
    } else {
#pragma unroll
        for (int j = 0; j < 4; ++j) {
            int cl = cslot + 8 * j;
            float m = -1e37f;
            for (int w = ws; w < we; ++w)
                m = fmaxf(m, smax[cl * WST + (w - wlo)]);
            out[obase + (size_t)(8 * j) * (PHB * PWB)] = m;
        }
    }
}

extern "C" void kernel_launch(void* const* d_in, const int* in_sizes, int n_in,
                              void* d_out, int out_size, void* d_ws, size_t ws_size,
                              hipStream_t stream) {
    const float* feats = (const float*)d_in[0];
    const float* rois  = (const float*)d_in[1];
    float* out = (float*)d_out;

    const int Cc = 128, Hc = 64, Wc = 512;
    int nroi = in_sizes[1] / 5;
    int blocks = nroi * PHB * (Cc / CHB);   // (n, ph, channel-quarter) = 8192

    ocr_roi_pool_kernel<<<blocks, BLK, 0, stream>>>(feats, rois, out, Cc, Hc, Wc);
}

// Round 6
// 34.937 us; speedup vs baseline: 1.6181x; 1.0261x over previous
//
#include <hip/hip_runtime.h>

// ROI max-pool (aspect-preserving "OCR" variant) — separable two-phase, v3.
// feats: (B=4, C=128, H=64, W=512) fp32
// rois:  (N, 5) fp32 = [batch, x1, y1, x2, y2] image coords, spatial scale 0.25
// out:   (N, C, PH=8, PW=32) fp32
//
// Block = (roi, ph, channel-quarter of 32). 256 thr = 32 w-lanes x 8 cslots,
// each cslot covers 4 channels (stride 8). Phase 1: rowmax over h -> LDS via
// float4 loads on a 4-aligned window (one dwordx4 per lane covers WST).
// Phase 2: w-max from LDS. LDS ~14.5 KB -> occupancy capped by waves.

#define PHB 8
#define PWB 32
#define CHB 32          // channels per block
#define WST 116         // staged width cap: ceil(32*bsw) <= 108, +3 align
#define BLK 256

static __device__ __forceinline__ float4 max4(float4 a, float4 b) {
    float4 r;
    r.x = fmaxf(a.x, b.x); r.y = fmaxf(a.y, b.y);
    r.z = fmaxf(a.z, b.z); r.w = fmaxf(a.w, b.w);
    return r;
}

__global__ __launch_bounds__(BLK) void ocr_roi_pool_kernel(
    const float* __restrict__ feats,
    const float* __restrict__ rois,
    float* __restrict__ out,
    int Cc, int Hc, int Wc)
{
#pragma clang fp contract(off)
    __shared__ float smax[CHB * WST];

    int b  = blockIdx.x;               // ((n*8 + ph)*4 + cq)
    int cq = b & 3;
    int ph = (b >> 2) & 7;
    int n  = b >> 5;
    int c0 = cq * CHB;

    // ---- ROI params: block-uniform -> scalar ----
    const float* r = rois + n * 5;
    int rb  = (int)r[0];
    int rsw = (int)floorf(r[1] * 0.25f + 0.5f);
    int rsh = (int)floorf(r[2] * 0.25f + 0.5f);
    int rew = (int)floorf(r[3] * 0.25f + 0.5f);
    int reh = (int)floorf(r[4] * 0.25f + 0.5f);

    int roi_w = max(rew - rsw + 1, 1);
    int roi_h = max(reh - rsh + 1, 1);
    int rpw   = (PHB * roi_w + roi_h - 1) / roi_h;

    float bsh = (float)roi_h / (float)PHB;
    float bsw = (float)roi_w / (float)rpw;

    // h-range for this ph (uniform over block), exact reference math
    int hs = (int)floorf((float)ph * bsh) + rsh;
    int he = (int)ceilf((float)(ph + 1) * bsh) + rsh;
    hs = min(max(hs, 0), Hc);
    he = min(max(he, 0), Hc);

    // staged w-window: covers every NON-PAD bin's reads; 4-aligned base.
    int wlo = min(max(rsw, 0), Wc);
    int whi = (int)ceilf((float)PWB * bsw) + rsw;
    whi = min(whi, rew + 4);
    whi = min(max(whi, 0), Wc);
    int wlo_al = wlo & ~3;
    int wwid = min(whi - wlo_al, WST);

    int t      = threadIdx.x;
    int lane_w = t & 31;
    int cslot  = t >> 5;               // 0..7
    int wp4    = lane_w * 4;           // this lane's 4-column slot

    const int plane_stride = Hc * Wc;  // 32768

    // ---- Phase 1: rowmax -> LDS (float4 loads, h unrolled x2) ----
    if (he > hs && wp4 < wwid) {
        const float* plane =
            feats + ((size_t)(rb * Cc + c0 + cslot) * Hc) * Wc;
        float4 rm[4];
#pragma unroll
        for (int j = 0; j < 4; ++j)
            rm[j] = make_float4(-1e37f, -1e37f, -1e37f, -1e37f);
        for (int h = hs; h < he; h += 2) {
            int hb   = min(h + 1, he - 1);
            int offa = h  * Wc + wlo_al + wp4;   // 16B-aligned, in-row
            int offb = hb * Wc + wlo_al + wp4;
#pragma unroll
            for (int j = 0; j < 4; ++j) {
                const float* pj = plane + (size_t)(8 * j) * plane_stride;
                float4 va = *reinterpret_cast<const float4*>(pj + offa);
                float4 vb = *reinterpret_cast<const float4*>(pj + offb);
                rm[j] = max4(rm[j], max4(va, vb));
            }
        }
#pragma unroll
        for (int j = 0; j < 4; ++j)   // 464B row stride: 16B-aligned
            *reinterpret_cast<float4*>(&smax[(cslot + 8 * j) * WST + wp4]) = rm[j];
    }
    __syncthreads();

    // ---- Phase 2: colmax from LDS, store ----
    int pw = lane_w;
    int ws = (int)floorf((float)pw * bsw) + rsw;
    int we = (int)ceilf((float)(pw + 1) * bsw) + rsw;
    ws = min(max(ws, 0), Wc);
    we = min(max(we, 0), Wc);

    bool pad   = (ws >= rew);
    bool empty = (he <= hs) || (we <= ws);

    size_t obase = (((size_t)n * Cc + c0 + cslot) * PHB + ph) * PWB + pw;
    if (pad || empty) {
#pragma unroll
        for (int j = 0; j < 4; ++j)
            out[obase + (size_t)(8 * j) * (PHB * PWB)] = 0.0f;
    } else {
#pragma unroll
        for (int j = 0; j < 4; ++j) {
            int cl = cslot + 8 * j;
            float m = -1e37f;
            for (int w = ws; w < we; ++w)
                m = fmaxf(m, smax[cl * WST + (w - wlo_al)]);
            out[obase + (size_t)(8 * j) * (PHB * PWB)] = m;
        }
    }
}

extern "C" void kernel_launch(void* const* d_in, const int* in_sizes, int n_in,
                              void* d_out, int out_size, void* d_ws, size_t ws_size,
                              hipStream_t stream) {
    const float* feats = (const float*)d_in[0];
    const float* rois  = (const float*)d_in[1];
    float* out = (float*)d_out;

    const int Cc = 128, Hc = 64, Wc = 512;
    int nroi = in_sizes[1] / 5;
    int blocks = nroi * PHB * (Cc / CHB);   // 8192

    ocr_roi_pool_kernel<<<blocks, BLK, 0, stream>>>(feats, rois, out, Cc, Hc, Wc);
}